// Round 3
// baseline (297.058 us; speedup 1.0000x reference)
//
#include <hip/hip_runtime.h>

#define V_DIM   4096
#define D_DIM   256
#define P_CNT   11
#define NB      128           // blocks per piece (phase 1)
#define ROWS_PB 32            // 4096 / NB rows per block
#define NBLK    (P_CNT * NB)  // 1408 phase-1 blocks
#define P2_BLK  128           // phase-2 blocks
#define P2_ROWS 32            // codebook rows per phase-2 block (4096/128)

// ---------------------------------------------------------------------------
// Phase 1: per-row softmax over V=4096, accumulate per-block partial mass.
// One block = 256 threads = 4 waves handles 32 consecutive rows.
//
// Changes vs R2:
//  - raw s_barrier with lgkmcnt-only wait: __syncthreads() emits
//    "s_waitcnt vmcnt(0) lgkmcnt(0)" which drains the row-r+1 prefetch at
//    every barrier. We only need the LDS red[] write ordered, so emit
//    s_waitcnt lgkmcnt(0) + s_barrier directly; prefetch loads stay in
//    flight across the barrier.
//  - no atomics: block writes its 4096-float partial to ws with plain
//    coalesced float4 stores; a separate tiny kernel reduces 128 partials
//    per piece into mass. (Old path: 5.8M f32 atomics onto 180KB.)
//  - no max subtraction (inputs bounded: x <= ~17.7, exp <= 4.6e7,
//    row sum <= 1.9e11 — safely inside f32).
// ---------------------------------------------------------------------------
__global__ __launch_bounds__(256) void phase1_softmax_part(
    const float* __restrict__ logits,
    const float* __restrict__ gumbel,
    float* __restrict__ part)
{
    const int t    = threadIdx.x;
    const int lane = t & 63;
    const int wid  = t >> 6;
    const int b    = blockIdx.x;
    const size_t row0 = (size_t)b * ROWS_PB;

    __shared__ float red[8];            // [0..3] even rows, [4..7] odd rows

    float acc[16];
#pragma unroll
    for (int k = 0; k < 16; ++k) acc[k] = 0.f;

    const float4* lg = (const float4*)(logits + row0 * (size_t)V_DIM);
    const float4* gn = (const float4*)(gumbel + row0 * (size_t)V_DIM);
    // row stride = V_DIM/4 = 1024 float4

    // prologue: load row 0
    float4 a[4], g[4];
#pragma unroll
    for (int k = 0; k < 4; ++k) {
        a[k] = lg[t + 256 * k];
        g[k] = gn[t + 256 * k];
    }

    for (int r = 0; r < ROWS_PB; ++r) {
        // ---- prefetch row r+1; stays in flight across the raw barrier ----
        float4 a2[4], g2[4];
        const bool more = (r + 1 < ROWS_PB);
        if (more) {
            const float4* lg2 = lg + (size_t)(r + 1) * 1024;
            const float4* gn2 = gn + (size_t)(r + 1) * 1024;
#pragma unroll
            for (int k = 0; k < 4; ++k) {
                a2[k] = lg2[t + 256 * k];
                g2[k] = gn2[t + 256 * k];
            }
        }

        // ---- exp (no max shift) + thread partial sum ----
        float e[16];
        float s = 0.f;
#pragma unroll
        for (int k = 0; k < 4; ++k) {
            e[4 * k + 0] = __expf(a[k].x + g[k].x);
            e[4 * k + 1] = __expf(a[k].y + g[k].y);
            e[4 * k + 2] = __expf(a[k].z + g[k].z);
            e[4 * k + 3] = __expf(a[k].w + g[k].w);
            s += (e[4 * k + 0] + e[4 * k + 1]) + (e[4 * k + 2] + e[4 * k + 3]);
        }

        // ---- block sum: wave shuffle + 4-slot LDS exchange ----
#pragma unroll
        for (int off = 32; off >= 1; off >>= 1)
            s += __shfl_xor(s, off, 64);
        const int slot = (r & 1) << 2;
        if (lane == 0) red[slot + wid] = s;
        // order the LDS write only; do NOT drain vmcnt (prefetch in flight)
        asm volatile("s_waitcnt lgkmcnt(0)" ::: "memory");
        __builtin_amdgcn_s_barrier();
        asm volatile("" ::: "memory");   // no hoisting of the reads above
        s = (red[slot + 0] + red[slot + 1]) + (red[slot + 2] + red[slot + 3]);
        const float inv = 1.f / s;

        // parity slots: row r+2's write to red[slot] is separated from row
        // r's reads by barrier r+1, so one barrier per row is race-free.

#pragma unroll
        for (int k = 0; k < 16; ++k) acc[k] += e[k] * inv;

        if (more) {
#pragma unroll
            for (int k = 0; k < 4; ++k) { a[k] = a2[k]; g[k] = g2[k]; }
        }
    }

    // plain coalesced partial store (no atomics)
    float4* pp = (float4*)(part + (size_t)b * V_DIM);
#pragma unroll
    for (int k = 0; k < 4; ++k)
        pp[t + 256 * k] = make_float4(acc[4 * k + 0], acc[4 * k + 1],
                                      acc[4 * k + 2], acc[4 * k + 3]);
}

// ---------------------------------------------------------------------------
// Phase 1b: mass[p][v] = sum over the piece's 128 block partials.
// grid = (V_DIM/256, P_CNT); 23 MB read, deterministic order.
// ---------------------------------------------------------------------------
__global__ __launch_bounds__(256) void phase1b_reduce_mass(
    const float* __restrict__ part,
    float* __restrict__ mass)
{
    const int v = blockIdx.x * 256 + threadIdx.x;
    const int p = blockIdx.y;
    const float* pp = part + (size_t)p * NB * V_DIM + v;
    float s = 0.f;
#pragma unroll 8
    for (int sub = 0; sub < NB; ++sub) s += pp[(size_t)sub * V_DIM];
    mass[(size_t)p * V_DIM + v] = s;
}

// ---------------------------------------------------------------------------
// Phase 2: partial[d] = sum over this block's 32 codebook rows v of
//          sum_p mass[p,v] * base[v, (d - 16p) & 255]
// ---------------------------------------------------------------------------
__global__ __launch_bounds__(256) void phase2_contract(
    const float* __restrict__ mass,
    const float* __restrict__ base,
    float* __restrict__ partial)
{
    __shared__ float sv[P2_ROWS][D_DIM];   // 32 KiB
    __shared__ float mt[P_CNT][P2_ROWS];

    const int t  = threadIdx.x;
    const int b  = blockIdx.x;
    const int v0 = b * P2_ROWS;

    const float4* bp  = (const float4*)(base + (size_t)v0 * D_DIM);
    float4*       svp = (float4*)&sv[0][0];
#pragma unroll
    for (int k = 0; k < 8; ++k) svp[t + 256 * k] = bp[t + 256 * k];

    for (int i = t; i < P_CNT * P2_ROWS; i += 256) {
        const int p  = i / P2_ROWS;
        const int vv = i - p * P2_ROWS;
        mt[p][vv] = mass[(size_t)p * V_DIM + v0 + vv];
    }
    __syncthreads();

    float a = 0.f;
    for (int v = 0; v < P2_ROWS; ++v) {
#pragma unroll
        for (int p = 0; p < P_CNT; ++p)
            a += mt[p][v] * sv[v][(t - 16 * p) & 255];
    }
    partial[(size_t)b * D_DIM + t] = a;
}

// ---------------------------------------------------------------------------
// Phase 3: out[d] = sum over 128 partials (deterministic final reduce)
// ---------------------------------------------------------------------------
__global__ __launch_bounds__(256) void phase3_reduce(
    const float* __restrict__ partial,
    float* __restrict__ out)
{
    const int t = threadIdx.x;
    float s = 0.f;
#pragma unroll 8
    for (int b = 0; b < P2_BLK; ++b) s += partial[(size_t)b * D_DIM + t];
    out[t] = s;
}

extern "C" void kernel_launch(void* const* d_in, const int* in_sizes, int n_in,
                              void* d_out, int out_size, void* d_ws, size_t ws_size,
                              hipStream_t stream)
{
    // input order: active_features(int32), indices_logits(f32 F*V),
    //              shared_vectors_base(f32 V*D), gumbel_noise(f32 B*F*V)
    const float* logits = (const float*)d_in[1];
    const float* base   = (const float*)d_in[2];
    const float* gumbel = (const float*)d_in[3];
    float* out = (float*)d_out;

    // ws layout: part[1408*4096] | mass[11*4096] | partial[128*256]
    float* part    = (float*)d_ws;
    float* mass    = part + (size_t)NBLK * V_DIM;
    float* partial = mass + (size_t)P_CNT * V_DIM;

    phase1_softmax_part<<<dim3(NBLK), 256, 0, stream>>>(logits, gumbel, part);
    phase1b_reduce_mass<<<dim3(V_DIM / 256, P_CNT), 256, 0, stream>>>(part, mass);
    phase2_contract<<<dim3(P2_BLK), 256, 0, stream>>>(mass, base, partial);
    phase3_reduce<<<dim3(1), 256, 0, stream>>>(partial, out);
}

// Round 4
// 278.199 us; speedup vs baseline: 1.0678x; 1.0678x over previous
//
#include <hip/hip_runtime.h>

#define V_DIM   4096
#define D_DIM   256
#define P_CNT   11
#define ROWS_PB 64            // rows per phase-1 block (64 | 4096 -> one piece/block)
#define NBLK    (P_CNT * V_DIM / ROWS_PB)   // 704 blocks: all co-resident at 4 blk/CU
#define P2_BLK  128           // phase-2 blocks
#define P2_ROWS 32            // codebook rows per phase-2 block (4096/128)

// ---------------------------------------------------------------------------
// Phase 1: per-row softmax over V=4096, accumulate per-piece mass (11,4096).
// One block = 256 threads = 4 waves handles 64 consecutive rows of ONE piece.
//
// R4 changes:
//  - back to atomic mass accumulation (R3's partial-store path added 46 MB
//    of ws traffic + a dispatch for zero benefit; atomics on the 180 KB
//    L2-resident mass buffer were free).
//  - 704 blocks x 64 rows instead of 1408 x 32: with __launch_bounds__(256,4)
//    (<=128 VGPR -> 4 blocks/CU -> 1024 resident slots) ALL blocks are
//    co-resident -> no second dispatch round at 1.5 blocks/CU starving HBM.
//  - keep: no max subtraction (x <= ~17.7 -> exp <= 4.6e7, sum <= 1.9e11,
//    safe in f32), next-row register prefetch, one raw s_barrier per row
//    with lgkmcnt-only wait (prefetch loads stay in flight).
// ---------------------------------------------------------------------------
__global__ __launch_bounds__(256, 4) void phase1_softmax_mass(
    const float* __restrict__ logits,
    const float* __restrict__ gumbel,
    float* __restrict__ mass)
{
    const int t    = threadIdx.x;
    const int lane = t & 63;
    const int wid  = t >> 6;
    const int b    = blockIdx.x;
    const int p    = b >> 6;                 // 64 blocks per piece
    const size_t row0 = (size_t)b * ROWS_PB;

    __shared__ float red[8];                 // [0..3] even rows, [4..7] odd

    float acc[16];
#pragma unroll
    for (int k = 0; k < 16; ++k) acc[k] = 0.f;

    const float4* lg = (const float4*)(logits + row0 * (size_t)V_DIM);
    const float4* gn = (const float4*)(gumbel + row0 * (size_t)V_DIM);
    // row stride = V_DIM/4 = 1024 float4

    // prologue: load row 0
    float4 a[4], g[4];
#pragma unroll
    for (int k = 0; k < 4; ++k) {
        a[k] = lg[t + 256 * k];
        g[k] = gn[t + 256 * k];
    }

    for (int r = 0; r < ROWS_PB; ++r) {
        // ---- prefetch row r+1; stays in flight across the raw barrier ----
        float4 a2[4], g2[4];
        const bool more = (r + 1 < ROWS_PB);
        if (more) {
            const float4* lg2 = lg + (size_t)(r + 1) * 1024;
            const float4* gn2 = gn + (size_t)(r + 1) * 1024;
#pragma unroll
            for (int k = 0; k < 4; ++k) {
                a2[k] = lg2[t + 256 * k];
                g2[k] = gn2[t + 256 * k];
            }
        }

        // ---- exp (no max shift) + thread partial sum ----
        float e[16];
        float s = 0.f;
#pragma unroll
        for (int k = 0; k < 4; ++k) {
            e[4 * k + 0] = __expf(a[k].x + g[k].x);
            e[4 * k + 1] = __expf(a[k].y + g[k].y);
            e[4 * k + 2] = __expf(a[k].z + g[k].z);
            e[4 * k + 3] = __expf(a[k].w + g[k].w);
            s += (e[4 * k + 0] + e[4 * k + 1]) + (e[4 * k + 2] + e[4 * k + 3]);
        }

        // ---- block sum: wave shuffle + 4-slot LDS exchange, one barrier ----
#pragma unroll
        for (int off = 32; off >= 1; off >>= 1)
            s += __shfl_xor(s, off, 64);
        const int slot = (r & 1) << 2;
        if (lane == 0) red[slot + wid] = s;
        // order the LDS write only; do NOT drain vmcnt (prefetch in flight)
        asm volatile("s_waitcnt lgkmcnt(0)" ::: "memory");
        __builtin_amdgcn_s_barrier();
        asm volatile("" ::: "memory");       // keep LDS reads below barrier
        s = (red[slot + 0] + red[slot + 1]) + (red[slot + 2] + red[slot + 3]);
        const float inv = 1.f / s;
        // parity slots: row r+2's write to red[slot] is separated from row
        // r's reads by barrier r+1 -> one barrier per row is race-free.

#pragma unroll
        for (int k = 0; k < 16; ++k) acc[k] += e[k] * inv;

        if (more) {
#pragma unroll
            for (int k = 0; k < 4; ++k) { a[k] = a2[k]; g[k] = g2[k]; }
        }
    }

    float* mp = mass + (size_t)p * V_DIM;
#pragma unroll
    for (int k = 0; k < 4; ++k) {
        const int j = 4 * (t + 256 * k);
        atomicAdd(mp + j + 0, acc[4 * k + 0]);
        atomicAdd(mp + j + 1, acc[4 * k + 1]);
        atomicAdd(mp + j + 2, acc[4 * k + 2]);
        atomicAdd(mp + j + 3, acc[4 * k + 3]);
    }
}

// ---------------------------------------------------------------------------
// Phase 2: partial[d] = sum over this block's 32 codebook rows v of
//          sum_p mass[p,v] * base[v, (d - 16p) & 255]
// ---------------------------------------------------------------------------
__global__ __launch_bounds__(256) void phase2_contract(
    const float* __restrict__ mass,
    const float* __restrict__ base,
    float* __restrict__ partial)
{
    __shared__ float sv[P2_ROWS][D_DIM];   // 32 KiB
    __shared__ float mt[P_CNT][P2_ROWS];

    const int t  = threadIdx.x;
    const int b  = blockIdx.x;
    const int v0 = b * P2_ROWS;

    const float4* bp  = (const float4*)(base + (size_t)v0 * D_DIM);
    float4*       svp = (float4*)&sv[0][0];
#pragma unroll
    for (int k = 0; k < 8; ++k) svp[t + 256 * k] = bp[t + 256 * k];

    for (int i = t; i < P_CNT * P2_ROWS; i += 256) {
        const int p  = i / P2_ROWS;
        const int vv = i - p * P2_ROWS;
        mt[p][vv] = mass[(size_t)p * V_DIM + v0 + vv];
    }
    __syncthreads();

    float a = 0.f;
    for (int v = 0; v < P2_ROWS; ++v) {
#pragma unroll
        for (int p = 0; p < P_CNT; ++p)
            a += mt[p][v] * sv[v][(t - 16 * p) & 255];
    }
    partial[(size_t)b * D_DIM + t] = a;
}

// ---------------------------------------------------------------------------
// Phase 3: out[d] = sum over 128 partials (deterministic final reduce)
// ---------------------------------------------------------------------------
__global__ __launch_bounds__(256) void phase3_reduce(
    const float* __restrict__ partial,
    float* __restrict__ out)
{
    const int t = threadIdx.x;
    float s = 0.f;
#pragma unroll 8
    for (int b = 0; b < P2_BLK; ++b) s += partial[(size_t)b * D_DIM + t];
    out[t] = s;
}

extern "C" void kernel_launch(void* const* d_in, const int* in_sizes, int n_in,
                              void* d_out, int out_size, void* d_ws, size_t ws_size,
                              hipStream_t stream)
{
    // input order: active_features(int32), indices_logits(f32 F*V),
    //              shared_vectors_base(f32 V*D), gumbel_noise(f32 B*F*V)
    const float* logits = (const float*)d_in[1];
    const float* base   = (const float*)d_in[2];
    const float* gumbel = (const float*)d_in[3];
    float* out = (float*)d_out;

    // ws layout: mass[11*4096] | partial[128*256]
    float* mass    = (float*)d_ws;
    float* partial = mass + (size_t)P_CNT * V_DIM;

    hipMemsetAsync(d_ws, 0, (size_t)P_CNT * V_DIM * sizeof(float), stream);

    phase1_softmax_mass<<<dim3(NBLK), 256, 0, stream>>>(logits, gumbel, mass);
    phase2_contract<<<dim3(P2_BLK), 256, 0, stream>>>(mass, base, partial);
    phase3_reduce<<<dim3(1), 256, 0, stream>>>(partial, out);
}

// Round 6
// 248.746 us; speedup vs baseline: 1.1942x; 1.1184x over previous
//
#include <hip/hip_runtime.h>

#define V_DIM   4096
#define D_DIM   256
#define P_CNT   11
#define ROWS_PB 64            // rows per phase-1 block (64 | 4096 -> one piece/block)
#define NBLK    (P_CNT * V_DIM / ROWS_PB)   // 704 blocks: all co-resident at 4 blk/CU
#define P2_BLK  128           // phase-2 blocks
#define P2_ROWS 32            // codebook rows per phase-2 block (4096/128)

// native clang vector type: __builtin_nontemporal_load requires a pointer to
// a scalar or clang ext_vector type (HIP_vector_type float4 is a struct).
typedef float f32x4 __attribute__((ext_vector_type(4)));

// ---------------------------------------------------------------------------
// Phase 1: per-row softmax over V=4096, accumulate per-piece mass (11,4096).
// One block = 256 threads = 4 waves handles 64 consecutive rows of ONE piece.
//
// R6 = R5 with the nontemporal builtin applied to a native vector type:
//  - loads grouped per stream: 4x 16B from logits as one burst, then 4x from
//    gumbel (was a0,g0,a1,g1... ping-pong between buffers 738MB apart).
//  - nontemporal (nt) loads on both streams: touched exactly once; skip L2
//    allocation (1.48GB of fill/evict through TCC for zero reuse).
// Kept from R4: 704 blocks x 64 rows all co-resident (launch_bounds(256,4)),
//  no max subtraction (x <= ~17.7, exp <= 4.6e7, sum <= 1.9e11 - f32 safe),
//  depth-1 register prefetch, one raw s_barrier per row with lgkmcnt-only
//  wait (prefetch stays in flight across the barrier), atomic mass flush
//  (measured ~free: R2 vs R3).
// ---------------------------------------------------------------------------
__global__ __launch_bounds__(256, 4) void phase1_softmax_mass(
    const float* __restrict__ logits,
    const float* __restrict__ gumbel,
    float* __restrict__ mass)
{
    const int t    = threadIdx.x;
    const int lane = t & 63;
    const int wid  = t >> 6;
    const int b    = blockIdx.x;
    const int p    = b >> 6;                 // 64 blocks per piece
    const size_t row0 = (size_t)b * ROWS_PB;

    __shared__ float red[8];                 // [0..3] even rows, [4..7] odd

    float acc[16];
#pragma unroll
    for (int k = 0; k < 16; ++k) acc[k] = 0.f;

    const f32x4* lg = (const f32x4*)(logits + row0 * (size_t)V_DIM);
    const f32x4* gn = (const f32x4*)(gumbel + row0 * (size_t)V_DIM);
    // row stride = V_DIM/4 = 1024 vectors

    // prologue: load row 0 (stream-grouped bursts)
    f32x4 a[4], g[4];
#pragma unroll
    for (int k = 0; k < 4; ++k) a[k] = __builtin_nontemporal_load(lg + t + 256 * k);
#pragma unroll
    for (int k = 0; k < 4; ++k) g[k] = __builtin_nontemporal_load(gn + t + 256 * k);

    for (int r = 0; r < ROWS_PB; ++r) {
        // ---- prefetch row r+1; stays in flight across the raw barrier ----
        f32x4 a2[4], g2[4];
        const bool more = (r + 1 < ROWS_PB);
        if (more) {
            const f32x4* lg2 = lg + (size_t)(r + 1) * 1024 + t;
            const f32x4* gn2 = gn + (size_t)(r + 1) * 1024 + t;
#pragma unroll
            for (int k = 0; k < 4; ++k) a2[k] = __builtin_nontemporal_load(lg2 + 256 * k);
#pragma unroll
            for (int k = 0; k < 4; ++k) g2[k] = __builtin_nontemporal_load(gn2 + 256 * k);
        }

        // ---- exp (no max shift) + thread partial sum ----
        float e[16];
        float s = 0.f;
#pragma unroll
        for (int k = 0; k < 4; ++k) {
            e[4 * k + 0] = __expf(a[k].x + g[k].x);
            e[4 * k + 1] = __expf(a[k].y + g[k].y);
            e[4 * k + 2] = __expf(a[k].z + g[k].z);
            e[4 * k + 3] = __expf(a[k].w + g[k].w);
            s += (e[4 * k + 0] + e[4 * k + 1]) + (e[4 * k + 2] + e[4 * k + 3]);
        }

        // ---- block sum: wave shuffle + 4-slot LDS exchange, one barrier ----
#pragma unroll
        for (int off = 32; off >= 1; off >>= 1)
            s += __shfl_xor(s, off, 64);
        const int slot = (r & 1) << 2;
        if (lane == 0) red[slot + wid] = s;
        // order the LDS write only; do NOT drain vmcnt (prefetch in flight)
        asm volatile("s_waitcnt lgkmcnt(0)" ::: "memory");
        __builtin_amdgcn_s_barrier();
        asm volatile("" ::: "memory");       // keep LDS reads below barrier
        s = (red[slot + 0] + red[slot + 1]) + (red[slot + 2] + red[slot + 3]);
        const float inv = 1.f / s;
        // parity slots: row r+2's write to red[slot] is separated from row
        // r's reads by barrier r+1 -> one barrier per row is race-free.

#pragma unroll
        for (int k = 0; k < 16; ++k) acc[k] += e[k] * inv;

        if (more) {
#pragma unroll
            for (int k = 0; k < 4; ++k) { a[k] = a2[k]; g[k] = g2[k]; }
        }
    }

    float* mp = mass + (size_t)p * V_DIM;
#pragma unroll
    for (int k = 0; k < 4; ++k) {
        const int j = 4 * (t + 256 * k);
        atomicAdd(mp + j + 0, acc[4 * k + 0]);
        atomicAdd(mp + j + 1, acc[4 * k + 1]);
        atomicAdd(mp + j + 2, acc[4 * k + 2]);
        atomicAdd(mp + j + 3, acc[4 * k + 3]);
    }
}

// ---------------------------------------------------------------------------
// Phase 2: partial[d] = sum over this block's 32 codebook rows v of
//          sum_p mass[p,v] * base[v, (d - 16p) & 255]
// ---------------------------------------------------------------------------
__global__ __launch_bounds__(256) void phase2_contract(
    const float* __restrict__ mass,
    const float* __restrict__ base,
    float* __restrict__ partial)
{
    __shared__ float sv[P2_ROWS][D_DIM];   // 32 KiB
    __shared__ float mt[P_CNT][P2_ROWS];

    const int t  = threadIdx.x;
    const int b  = blockIdx.x;
    const int v0 = b * P2_ROWS;

    const float4* bp  = (const float4*)(base + (size_t)v0 * D_DIM);
    float4*       svp = (float4*)&sv[0][0];
#pragma unroll
    for (int k = 0; k < 8; ++k) svp[t + 256 * k] = bp[t + 256 * k];

    for (int i = t; i < P_CNT * P2_ROWS; i += 256) {
        const int p  = i / P2_ROWS;
        const int vv = i - p * P2_ROWS;
        mt[p][vv] = mass[(size_t)p * V_DIM + v0 + vv];
    }
    __syncthreads();

    float a = 0.f;
    for (int v = 0; v < P2_ROWS; ++v) {
#pragma unroll
        for (int p = 0; p < P_CNT; ++p)
            a += mt[p][v] * sv[v][(t - 16 * p) & 255];
    }
    partial[(size_t)b * D_DIM + t] = a;
}

// ---------------------------------------------------------------------------
// Phase 3: out[d] = sum over 128 partials (deterministic final reduce)
// ---------------------------------------------------------------------------
__global__ __launch_bounds__(256) void phase3_reduce(
    const float* __restrict__ partial,
    float* __restrict__ out)
{
    const int t = threadIdx.x;
    float s = 0.f;
#pragma unroll 8
    for (int b = 0; b < P2_BLK; ++b) s += partial[(size_t)b * D_DIM + t];
    out[t] = s;
}

extern "C" void kernel_launch(void* const* d_in, const int* in_sizes, int n_in,
                              void* d_out, int out_size, void* d_ws, size_t ws_size,
                              hipStream_t stream)
{
    // input order: active_features(int32), indices_logits(f32 F*V),
    //              shared_vectors_base(f32 V*D), gumbel_noise(f32 B*F*V)
    const float* logits = (const float*)d_in[1];
    const float* base   = (const float*)d_in[2];
    const float* gumbel = (const float*)d_in[3];
    float* out = (float*)d_out;

    // ws layout: mass[11*4096] | partial[128*256]
    float* mass    = (float*)d_ws;
    float* partial = mass + (size_t)P_CNT * V_DIM;

    (void)hipMemsetAsync(d_ws, 0, (size_t)P_CNT * V_DIM * sizeof(float), stream);

    phase1_softmax_mass<<<dim3(NBLK), 256, 0, stream>>>(logits, gumbel, mass);
    phase2_contract<<<dim3(P2_BLK), 256, 0, stream>>>(mass, base, partial);
    phase3_reduce<<<dim3(1), 256, 0, stream>>>(partial, out);
}